// Round 10
// baseline (316.824 us; speedup 1.0000x reference)
//
#include <hip/hip_runtime.h>
#include <math.h>

#define BB 512
#define TT 1024
#define KK 48
#define PF 6   // emission prefetch depth (register ring)

static constexpr float L2E = 1.4426950408889634f;   // log2(e)
static constexpr float LN2 = 0.6931471805599453f;   // ln(2)

__device__ __forceinline__ float wave_reduce_sum_f(float v) {
    #pragma unroll
    for (int m = 32; m >= 1; m >>= 1) v += __shfl_xor(v, m, 64);
    return v;
}
__device__ __forceinline__ int wave_reduce_sum_i(int v) {
    #pragma unroll
    for (int m = 32; m >= 1; m >>= 1) v += __shfl_xor(v, m, 64);
    return v;
}

__device__ __forceinline__ float rlane(float v, int i) {
    return __uint_as_float(__builtin_amdgcn_readlane(__float_as_uint(v), i));
}

// s = M . u  (u broadcast from lanes via v_readlane), 8 accumulators
__device__ __forceinline__ float matvec48(const float* __restrict__ M, float u) {
    float a[8];
    #pragma unroll
    for (int i = 0; i < 8; ++i) a[i] = 0.0f;
    #pragma unroll
    for (int i = 0; i < KK; ++i)
        a[i & 7] = fmaf(M[i], rlane(u, i), a[i & 7]);
    return (((a[0] + a[1]) + (a[2] + a[3])) + ((a[4] + a[5]) + (a[6] + a[7])));
}

// Fused: blocks [0,512) = numerator, blocks [512,1024) = denominator.
// Denominator normalizer is a POWER OF TWO: m = exponent(z) extracted with
// integer ops (exact, off the VALU-trans pipe); -m_prev folded into the
// emission exponent so E is computed entirely off the serial chain.
// This removes log2f/exp2f (suspected ~300 cy/step of dependent trans
// latency) from the recurrence chain — the round-10 hypothesis test.
__global__ __launch_bounds__(64, 1) void crf_fused(
    const float* __restrict__ emissions,   // (B, T, K)
    const int*   __restrict__ tags,        // (B, T)
    const void*  __restrict__ mask,        // (B, T) — dtype probed
    const float* __restrict__ transitions, // (K, K)
    const float* __restrict__ start_t,     // (K,)
    const float* __restrict__ end_t,       // (K,)
    float*       __restrict__ ws_s,        // (B,) path scores
    float*       __restrict__ ws_d)        // (B,) log-denominators
{
    const int lane = threadIdx.x;
    const unsigned w0 = *((const unsigned*)mask);

    if (blockIdx.x < BB) {
        // ===== numerator (verbatim from passing rounds) =====
        const int b = blockIdx.x;
        const float* em = emissions + (size_t)b * TT * KK;
        const int*   tg = tags      + (size_t)b * TT;
        int c = 0;
        if (w0 == 1u) {
            const int* mp = (const int*)mask + (size_t)b * TT;
            for (int t = lane; t < TT; t += 64) c += (mp[t] != 0);
        } else if (w0 == 0x3f800000u) {
            const float* mp = (const float*)mask + (size_t)b * TT;
            for (int t = lane; t < TT; t += 64) c += (mp[t] != 0.0f);
        } else {
            const unsigned char* mp = (const unsigned char*)mask + (size_t)b * TT;
            for (int t = lane; t < TT; t += 64) c += (mp[t] != 0);
        }
        const int L = wave_reduce_sum_i(c);
        float sc = 0.0f;
        for (int t = lane; t < TT; t += 64) {
            if (t < L) {
                const int tagt = tg[t];
                float term = em[(size_t)t * KK + tagt];
                term += (t == 0) ? start_t[tagt] : transitions[tg[t - 1] * KK + tagt];
                sc += term;
            }
        }
        sc = wave_reduce_sum_f(sc);
        if (lane == 0) ws_s[b] = sc + end_t[tg[L - 1]];
        return;
    }

    // ===== denominator: scaled linear-space forward, f32 state =====
    const int b = blockIdx.x - BB;
    const float* em = emissions + (size_t)b * TT * KK;

    int c = 0;
    if (w0 == 1u) {
        const int* mp = (const int*)mask + (size_t)b * TT;
        for (int t = lane; t < TT; t += 64) c += (mp[t] != 0);
    } else if (w0 == 0x3f800000u) {
        const float* mp = (const float*)mask + (size_t)b * TT;
        for (int t = lane; t < TT; t += 64) c += (mp[t] != 0.0f);
    } else {
        const unsigned char* mp = (const unsigned char*)mask + (size_t)b * TT;
        for (int t = lane; t < TT; t += 64) c += (mp[t] != 0);
    }
    const int L = wave_reduce_sum_i(c);

    const int j  = lane;
    const int jj = (j < KK) ? j : 0;
    float M[KK];
    #pragma unroll
    for (int i = 0; i < KK; ++i) M[i] = exp2f(transitions[jj * KK + i] * L2E);

    // init: u0[j] = 2^(A0 - C0); u0[0] = 1 exactly => m0 = 0
    const float A0 = (start_t[jj] + em[jj]) * L2E;
    const float C0 = rlane(A0, 0);
    float u  = exp2f(A0 - C0);
    float nm = 0.0f;      // -(m_prev): minus the pending pow2-normalizer exponent
    float CS = C0;        // running log2 offset (float adds of exact ints)

    float cur[PF];
    #pragma unroll
    for (int k = 0; k < PF; ++k) {
        const int tt = (1 + k < TT) ? (1 + k) : (TT - 1);
        cur[k] = em[(size_t)tt * KK + jj];
    }

    int t = 1;
    for (; t + PF <= L; t += PF) {
        float nxt[PF];
        #pragma unroll
        for (int k = 0; k < PF; ++k) {
            int tt = t + PF + k;
            tt = (tt < TT) ? tt : (TT - 1);
            nxt[k] = em[(size_t)tt * KK + jj];
        }
        #pragma unroll
        for (int k = 0; k < PF; ++k) {
            const float E = exp2f(fmaf(cur[k], L2E, nm));  // fully off-chain
            const float s = matvec48(M, u);
            u = s * E;
            CS -= nm;                                      // CS += m_prev (exact)
            // extract exponent of z = u[0] — integer ops, off-chain
            const float z = rlane(u, 0);
            const int   m = (int)((__float_as_uint(z) >> 23) & 0xFFu) - 127;
            nm = -(float)m;
        }
        #pragma unroll
        for (int k = 0; k < PF; ++k) cur[k] = nxt[k];
    }
    #pragma unroll
    for (int k = 0; k < PF; ++k) {
        if (t + k < L) {
            const float E = exp2f(fmaf(cur[k], L2E, nm));
            const float s = matvec48(M, u);
            u = s * E;
            CS -= nm;
            const float z = rlane(u, 0);
            const int   m = (int)((__float_as_uint(z) >> 23) & 0xFFu) - 127;
            nm = -(float)m;
        }
    }

    // log_den = ln2 * (CS + log2(sum_j u[j] * 2^(end[j]*L2E)))
    // (final unconsumed m correctly ignored — CS only counts consumed scalings)
    const float contrib = (j < KK) ? u * exp2f(end_t[jj] * L2E) : 0.0f;
    const float ssum    = wave_reduce_sum_f(contrib);
    if (lane == 0) ws_d[b] = LN2 * (CS + log2f(ssum));
}

__global__ __launch_bounds__(256) void crf_combine(
    const float* __restrict__ ws_s, const float* __restrict__ ws_d,
    float* __restrict__ out)
{
    const int i = blockIdx.x * 256 + threadIdx.x;
    if (i < BB) out[i] = ws_s[i] - ws_d[i];
}

extern "C" void kernel_launch(void* const* d_in, const int* in_sizes, int n_in,
                              void* d_out, int out_size, void* d_ws, size_t ws_size,
                              hipStream_t stream) {
    const float* emissions   = (const float*)d_in[0];
    const int*   tags        = (const int*)  d_in[1];
    const void*  mask        = (const void*) d_in[2];
    const float* transitions = (const float*)d_in[3];
    const float* start_t     = (const float*)d_in[4];
    const float* end_t       = (const float*)d_in[5];
    float* out  = (float*)d_out;
    float* ws_s = (float*)d_ws;          // 512 floats
    float* ws_d = ws_s + BB;             // 512 floats

    crf_fused<<<2 * BB, 64, 0, stream>>>(emissions, tags, mask, transitions,
                                         start_t, end_t, ws_s, ws_d);
    crf_combine<<<2, 256, 0, stream>>>(ws_s, ws_d, out);
}